// Round 6
// baseline (123.209 us; speedup 1.0000x reference)
//
#include <hip/hip_runtime.h>
#include <hip/hip_bf16.h>

typedef __bf16 bf16x8 __attribute__((ext_vector_type(8)));
typedef __bf16 bf16x4 __attribute__((ext_vector_type(4)));
typedef float  f32x4  __attribute__((ext_vector_type(4)));

#define NB 64
#define LL 1024
#define DD 64
#define PB 40   // bf16 stride for Pw rows (80 B)

#define NW 16                                    // waves per block
#define LDS_K_BYTES (LL * DD * 2)                // 128 KiB
#define LDS_TOTAL   (LDS_K_BYTES + NW * 16 * PB * 2)   // +20 KiB Pw

#if __has_builtin(__builtin_amdgcn_exp2f)
#define EXP2(x) __builtin_amdgcn_exp2f(x)
#else
#define EXP2(x) exp2f(x)
#endif

// ---------------- V pre-pass: transpose+convert V -> Vt bf16 [b][d][key] ----
__global__ __launch_bounds__(256)
void preconvert_v(const float* __restrict__ v, __bf16* __restrict__ vt) {
  const int blk = blockIdx.x, tid = threadIdx.x;
  const int b = blk >> 4, t = blk & 15;   // 64-key tile t of batch b
  __shared__ float tile[64][65];
  const float* src = v + ((size_t)b * LL + t * 64) * DD;
  for (int i = tid; i < 64 * 16; i += 256) {
    const int row = i >> 4, c4 = (i & 15) * 4;
    f32x4 x = *(const f32x4*)(src + row * DD + c4);
    tile[row][c4 + 0] = x[0]; tile[row][c4 + 1] = x[1];
    tile[row][c4 + 2] = x[2]; tile[row][c4 + 3] = x[3];
  }
  __syncthreads();
  __bf16* dst = vt + (size_t)b * DD * LL + t * 64;
  for (int i = tid; i < 64 * 8; i += 256) {
    const int d = i >> 3, k8 = (i & 7) * 8;
    bf16x8 o;
    #pragma unroll
    for (int j = 0; j < 8; ++j) o[j] = (__bf16)tile[k8 + j][d];
    *(bf16x8*)(dst + (size_t)d * LL + k8) = o;
  }
}

// ---------------- main: whole-K-in-LDS, 16 waves, staggered, nt stores ------
__global__ __launch_bounds__(1024, 1)
void sdpa_wide(const float* __restrict__ q, const float* __restrict__ kf,
               const __bf16* __restrict__ vt, const float* __restrict__ scale_p,
               float* __restrict__ out) {
  extern __shared__ char smem[];
  __bf16* Klds = (__bf16*)smem;                     // [1024][64], XOR-swizzled
  __bf16* Pw   = (__bf16*)(smem + LDS_K_BYTES);     // [NW][16][PB]

  const int tid  = threadIdx.x;
  const int lane = tid & 63;
  const int w    = tid >> 6;            // 0..15
  const int l15  = lane & 15;
  const int lg   = lane >> 4;

  int bid = blockIdx.x;                      // 256 blocks
  bid = (bid & 7) * 32 + (bid >> 3);         // XCD j -> batches [j*8, j*8+8)
  const int b     = bid >> 2;
  const int qrow0 = (bid & 3) * 256 + w * 16;   // this wave's 16 q rows

  const float scale2 = scale_p[0] * 1.4426950408889634f;  // fold log2(e)
  const float* kb = kf + (size_t)b * LL * DD;
  const __bf16* vb = vt + (size_t)b * DD * LL;
  float* ctxb  = out + ((size_t)b * LL + qrow0) * DD;
  float* attnb = out + (size_t)NB * LL * DD + (size_t)b * LL * LL
               + (size_t)qrow0 * LL;

  // ---- stage ALL of K: fp32 global -> bf16 LDS, swizzled (8 iters) ----
  #pragma unroll
  for (int it = 0; it < 8; ++it) {
    const int c = it * 1024 + tid;           // 8192 chunks of 8 elems
    const int row = c >> 3, slot = c & 7;
    const f32x4* s4 = (const f32x4*)(kb + (size_t)c * 8);
    f32x4 x0 = s4[0], x1 = s4[1];
    bf16x8 t;
    #pragma unroll
    for (int j = 0; j < 4; ++j) { t[j] = (__bf16)x0[j]; t[4 + j] = (__bf16)x1[j]; }
    *(bf16x8*)(Klds + row * 64 + ((slot * 8) ^ ((row & 7) * 8))) = t;
  }

  // ---- Q fragments (scale2 folded) ----
  bf16x8 aq[2];
  {
    const float* qrow = q + ((size_t)b * LL + qrow0 + l15) * DD;
    #pragma unroll
    for (int s = 0; s < 2; ++s) {
      const f32x4* p4 = (const f32x4*)(qrow + s * 32 + lg * 8);
      f32x4 x0 = p4[0], x1 = p4[1];
      #pragma unroll
      for (int j = 0; j < 4; ++j) {
        aq[s][j]     = (__bf16)(x0[j] * scale2);
        aq[s][4 + j] = (__bf16)(x1[j] * scale2);
      }
    }
  }

  __syncthreads();   // K resident — the only barrier

  const int xsw  = (l15 & 7) * 8;           // read-side swizzle
  const int woff = (w * 2) & 31;            // per-wave kt stagger
  __bf16* prow = Pw + (w * 16 + l15) * PB;

  // ================= pass 1: denominators ==================================
  float ls = 0.f;
  for (int kt = 0; kt < 32; ++kt) {
    const int kk = (kt + woff) & 31;
    bf16x8 bk[2][2];
    #pragma unroll
    for (int f = 0; f < 2; ++f)
      #pragma unroll
      for (int s = 0; s < 2; ++s)
        bk[f][s] = *(const bf16x8*)(Klds + (kk * 32 + f * 16 + l15) * 64
                                         + ((s * 32 + lg * 8) ^ xsw));
    f32x4 sacc[2] = {{0.f,0.f,0.f,0.f},{0.f,0.f,0.f,0.f}};
    #pragma unroll
    for (int s = 0; s < 2; ++s)
      #pragma unroll
      for (int f = 0; f < 2; ++f)
        sacc[f] = __builtin_amdgcn_mfma_f32_16x16x32_bf16(bk[f][s], aq[s], sacc[f], 0, 0, 0);
    #pragma unroll
    for (int f = 0; f < 2; ++f)
      #pragma unroll
      for (int r = 0; r < 4; ++r)
        ls += EXP2(sacc[f][r]);
  }
  ls += __shfl_xor(ls, 16, 64);
  ls += __shfl_xor(ls, 32, 64);
  const float rl = 1.0f / ls;

  // ================= pass 2: recompute, nt-store attn, PV ==================
  f32x4 cacc[4];
  #pragma unroll
  for (int g = 0; g < 4; ++g) cacc[g] = (f32x4){0.f, 0.f, 0.f, 0.f};

  // 2-deep V-fragment prefetch (kk-indexed, wraps; wrapped loads are benign)
  bf16x8 bvA[4], bvB[4];
  {
    const int k0 = woff, k1 = (woff + 1) & 31;
    #pragma unroll
    for (int g = 0; g < 4; ++g) {
      bvA[g] = *(const bf16x8*)(vb + (size_t)(g * 16 + l15) * LL + k0 * 32 + lg * 8);
      bvB[g] = *(const bf16x8*)(vb + (size_t)(g * 16 + l15) * LL + k1 * 32 + lg * 8);
    }
  }

  for (int kt = 0; kt < 32; ++kt) {
    const int kk  = (kt + woff) & 31;
    const int kk2 = (kt + 2 + woff) & 31;

    bf16x8 bvc[4];
    #pragma unroll
    for (int g = 0; g < 4; ++g) bvc[g] = bvA[g];
    #pragma unroll
    for (int g = 0; g < 4; ++g) bvA[g] = bvB[g];
    #pragma unroll
    for (int g = 0; g < 4; ++g)
      bvB[g] = *(const bf16x8*)(vb + (size_t)(g * 16 + l15) * LL + kk2 * 32 + lg * 8);

    bf16x8 bk[2][2];
    #pragma unroll
    for (int f = 0; f < 2; ++f)
      #pragma unroll
      for (int s = 0; s < 2; ++s)
        bk[f][s] = *(const bf16x8*)(Klds + (kk * 32 + f * 16 + l15) * 64
                                         + ((s * 32 + lg * 8) ^ xsw));

    f32x4 sacc[2] = {{0.f,0.f,0.f,0.f},{0.f,0.f,0.f,0.f}};
    #pragma unroll
    for (int s = 0; s < 2; ++s)
      #pragma unroll
      for (int f = 0; f < 2; ++f)
        sacc[f] = __builtin_amdgcn_mfma_f32_16x16x32_bf16(bk[f][s], aq[s], sacc[f], 0, 0, 0);

    // p = exp2(s) * rl (lane owns q = l15; k = kk*32 + f*16 + lg*4 + r)
    f32x4 pv[2];
    #pragma unroll
    for (int f = 0; f < 2; ++f)
      #pragma unroll
      for (int r = 0; r < 4; ++r)
        pv[f][r] = EXP2(sacc[f][r]) * rl;

    // PV A-operand through wave-private bf16 LDS (layout shuffle only)
    #pragma unroll
    for (int f = 0; f < 2; ++f) {
      bf16x4 pb;
      #pragma unroll
      for (int r = 0; r < 4; ++r) pb[r] = (__bf16)pv[f][r];
      *(bf16x4*)(prow + f * 16 + lg * 4) = pb;
    }
    bf16x8 pa = *(const bf16x8*)(prow + lg * 8);
    #pragma unroll
    for (int g = 0; g < 4; ++g)
      cacc[g] = __builtin_amdgcn_mfma_f32_16x16x32_bf16(pa, bvc[g], cacc[g], 0, 0, 0);

    // nontemporal attn stores LAST (keep stores newest in the vmcnt stream)
    float* arow = attnb + (size_t)l15 * LL + kk * 32 + lg * 4;
    __builtin_nontemporal_store(pv[0], (f32x4*)arow);
    __builtin_nontemporal_store(pv[1], (f32x4*)(arow + 16));
  }

  // ---- context epilogue ----
  #pragma unroll
  for (int g = 0; g < 4; ++g)
    #pragma unroll
    for (int r = 0; r < 4; ++r)
      ctxb[(size_t)(lg * 4 + r) * DD + g * 16 + l15] = cacc[g][r];
}

// ====================== fallback (R1 kernel, proven 151.7 µs) ===============
#define BQ 64
#define BK 32
#define KSTRIDE 72
#define VSTRIDE 40
#define PSTRIDE 48

__global__ __launch_bounds__(256, 4)
void sdpa_fallback(const float* __restrict__ q, const float* __restrict__ k,
                   const float* __restrict__ v, const float* __restrict__ scale_p,
                   float* __restrict__ out) {
  const int tid  = threadIdx.x;
  const int lane = tid & 63;
  const int w    = tid >> 6;
  int bid = blockIdx.x;
  bid = (bid & 7) * 128 + (bid >> 3);
  const int b    = bid >> 4;
  const int qblk = (bid & 15) * BQ;

  __shared__ __bf16 Ks[BK * KSTRIDE];
  __shared__ __bf16 Vs[DD * VSTRIDE];
  __shared__ __bf16 Pp[4][16 * PSTRIDE];

  const float scale = scale_p[0];
  const float* qb = q + ((size_t)b * LL + qblk) * DD;
  const float* kb = k + (size_t)b * LL * DD;
  const float* vb = v + (size_t)b * LL * DD;
  float* ctx  = out + ((size_t)b * LL + qblk) * DD;
  float* attn = out + (size_t)NB * LL * DD + (size_t)b * LL * LL + (size_t)qblk * LL;

  const int l15 = lane & 15;
  const int lg  = lane >> 4;
  const int dchunk = lg * 8;

  bf16x8 aq[2];
  {
    const float* qrow = qb + (size_t)(w * 16 + l15) * DD;
    #pragma unroll
    for (int s = 0; s < 2; ++s) {
      const f32x4* p4 = (const f32x4*)(qrow + s * 32 + dchunk);
      f32x4 x0 = p4[0], x1 = p4[1];
      #pragma unroll
      for (int j = 0; j < 4; ++j) {
        aq[s][j]     = (__bf16)(x0[j] * scale);
        aq[s][4 + j] = (__bf16)(x1[j] * scale);
      }
    }
  }

  const int srow = tid >> 3;
  const int sd0  = (tid & 7) * 8;

  float lpart[4] = {0.f, 0.f, 0.f, 0.f};
  for (int kt = 0; kt < LL / BK; ++kt) {
    __syncthreads();
    {
      const f32x4* src = (const f32x4*)(kb + (size_t)(kt * BK + srow) * DD + sd0);
      f32x4 x0 = src[0], x1 = src[1];
      bf16x8 t;
      #pragma unroll
      for (int j = 0; j < 4; ++j) { t[j] = (__bf16)x0[j]; t[4 + j] = (__bf16)x1[j]; }
      *(bf16x8*)&Ks[srow * KSTRIDE + sd0] = t;
    }
    __syncthreads();
    f32x4 sacc[2] = {{0.f,0.f,0.f,0.f},{0.f,0.f,0.f,0.f}};
    #pragma unroll
    for (int s = 0; s < 2; ++s)
      #pragma unroll
      for (int f = 0; f < 2; ++f) {
        bf16x8 bk = *(const bf16x8*)&Ks[(f * 16 + l15) * KSTRIDE + s * 32 + dchunk];
        sacc[f] = __builtin_amdgcn_mfma_f32_16x16x32_bf16(aq[s], bk, sacc[f], 0, 0, 0);
      }
    #pragma unroll
    for (int f = 0; f < 2; ++f)
      #pragma unroll
      for (int r = 0; r < 4; ++r)
        lpart[r] += __expf(sacc[f][r]);
  }
  #pragma unroll
  for (int m = 1; m < 16; m <<= 1)
    #pragma unroll
    for (int r = 0; r < 4; ++r)
      lpart[r] += __shfl_xor(lpart[r], m, 64);
  float rl[4];
  #pragma unroll
  for (int r = 0; r < 4; ++r) rl[r] = 1.0f / lpart[r];

  f32x4 cacc[4] = {{0.f,0.f,0.f,0.f},{0.f,0.f,0.f,0.f},
                   {0.f,0.f,0.f,0.f},{0.f,0.f,0.f,0.f}};
  for (int kt = 0; kt < LL / BK; ++kt) {
    __syncthreads();
    {
      const f32x4* src = (const f32x4*)(kb + (size_t)(kt * BK + srow) * DD + sd0);
      f32x4 x0 = src[0], x1 = src[1];
      bf16x8 t;
      #pragma unroll
      for (int j = 0; j < 4; ++j) { t[j] = (__bf16)x0[j]; t[4 + j] = (__bf16)x1[j]; }
      *(bf16x8*)&Ks[srow * KSTRIDE + sd0] = t;
      const f32x4* vsrc = (const f32x4*)(vb + (size_t)(kt * BK + srow) * DD + sd0);
      f32x4 y0 = vsrc[0], y1 = vsrc[1];
      #pragma unroll
      for (int j = 0; j < 4; ++j) {
        Vs[(sd0 + j)     * VSTRIDE + srow] = (__bf16)y0[j];
        Vs[(sd0 + 4 + j) * VSTRIDE + srow] = (__bf16)y1[j];
      }
    }
    __syncthreads();
    f32x4 sacc[2] = {{0.f,0.f,0.f,0.f},{0.f,0.f,0.f,0.f}};
    #pragma unroll
    for (int s = 0; s < 2; ++s)
      #pragma unroll
      for (int f = 0; f < 2; ++f) {
        bf16x8 bk = *(const bf16x8*)&Ks[(f * 16 + l15) * KSTRIDE + s * 32 + dchunk];
        sacc[f] = __builtin_amdgcn_mfma_f32_16x16x32_bf16(aq[s], bk, sacc[f], 0, 0, 0);
      }
    #pragma unroll
    for (int f = 0; f < 2; ++f)
      #pragma unroll
      for (int r = 0; r < 4; ++r) {
        const int row = lg * 4 + r;
        float p = __expf(sacc[f][r]) * rl[r];
        attn[(size_t)(w * 16 + row) * LL + (kt * BK + f * 16 + l15)] = p;
        Pp[w][row * PSTRIDE + f * 16 + l15] = (__bf16)p;
      }
    bf16x8 pa = *(const bf16x8*)&Pp[w][l15 * PSTRIDE + lg * 8];
    #pragma unroll
    for (int g = 0; g < 4; ++g) {
      bf16x8 bv = *(const bf16x8*)&Vs[(g * 16 + l15) * VSTRIDE + lg * 8];
      cacc[g] = __builtin_amdgcn_mfma_f32_16x16x32_bf16(pa, bv, cacc[g], 0, 0, 0);
    }
  }
  #pragma unroll
  for (int g = 0; g < 4; ++g)
    #pragma unroll
    for (int r = 0; r < 4; ++r)
      ctx[(size_t)(w * 16 + lg * 4 + r) * DD + g * 16 + l15] = cacc[g][r];
}

extern "C" void kernel_launch(void* const* d_in, const int* in_sizes, int n_in,
                              void* d_out, int out_size, void* d_ws, size_t ws_size,
                              hipStream_t stream) {
  const float* q = (const float*)d_in[0];
  const float* k = (const float*)d_in[1];
  const float* v = (const float*)d_in[2];
  const float* s = (const float*)d_in[3];
  float* out = (float*)d_out;

  const size_t vbytes = (size_t)NB * LL * DD * 2;   // 8 MB for V^T bf16
  if (ws_size >= vbytes) {
    __bf16* vt = (__bf16*)d_ws;
    preconvert_v<<<dim3(NB * (LL / 64)), dim3(256), 0, stream>>>(v, vt);
    (void)hipFuncSetAttribute((const void*)sdpa_wide,
                              hipFuncAttributeMaxDynamicSharedMemorySize,
                              LDS_TOTAL);
    sdpa_wide<<<dim3(256), dim3(1024), LDS_TOTAL, stream>>>(q, k, vt, s, out);
  } else {
    sdpa_fallback<<<dim3(NB * (LL / 64)), dim3(256), 0, stream>>>(q, k, v, s, out);
  }
}

// Round 7
// 107.791 us; speedup vs baseline: 1.1430x; 1.1430x over previous
//
#include <hip/hip_runtime.h>
#include <hip/hip_bf16.h>

typedef __bf16 bf16x8 __attribute__((ext_vector_type(8)));
typedef float  f32x4  __attribute__((ext_vector_type(4)));

#define NB 64
#define LL 1024
#define DD 64
#define HK 512          // keys per LDS half in main kernel
#define PSTR 36         // fp32 stride for Pw rows

#define LSUM_LDS  (LL * DD * 2)                            // 128 KiB
#define MAIN_LDS  (2 * HK * DD * 2 + 8 * 16 * PSTR * 4)    // 64+64+18 = 146 KiB

#define WS_VT_OFF 0
#define WS_RL_OFF ((size_t)8 * 1024 * 1024)
#define WS_NEED   (WS_RL_OFF + (size_t)NB * LL * 4)

#if __has_builtin(__builtin_amdgcn_exp2f)
#define EXP2(x) __builtin_amdgcn_exp2f(x)
#else
#define EXP2(x) exp2f(x)
#endif

// ---------------- V pre-pass: transpose+convert V -> Vt bf16 [b][d][key] ----
__global__ __launch_bounds__(256)
void preconvert_v(const float* __restrict__ v, __bf16* __restrict__ vt) {
  const int blk = blockIdx.x, tid = threadIdx.x;
  const int b = blk >> 4, t = blk & 15;
  __shared__ float tile[64][65];
  const float* src = v + ((size_t)b * LL + t * 64) * DD;
  for (int i = tid; i < 64 * 16; i += 256) {
    const int row = i >> 4, c4 = (i & 15) * 4;
    f32x4 x = *(const f32x4*)(src + row * DD + c4);
    tile[row][c4 + 0] = x[0]; tile[row][c4 + 1] = x[1];
    tile[row][c4 + 2] = x[2]; tile[row][c4 + 3] = x[3];
  }
  __syncthreads();
  __bf16* dst = vt + (size_t)b * DD * LL + t * 64;
  for (int i = tid; i < 64 * 8; i += 256) {
    const int d = i >> 3, k8 = (i & 7) * 8;
    bf16x8 o;
    #pragma unroll
    for (int j = 0; j < 8; ++j) o[j] = (__bf16)tile[k8 + j][d];
    *(bf16x8*)(dst + (size_t)d * LL + k8) = o;
  }
}

// ---------------- lsum: whole-K-in-LDS, denominators only -------------------
__global__ __launch_bounds__(512, 1)
void lsum_kernel(const float* __restrict__ q, const float* __restrict__ kf,
                 const float* __restrict__ scale_p, float* __restrict__ rlbuf) {
  extern __shared__ char smem[];
  __bf16* Klds = (__bf16*)smem;                 // [1024][64], XOR-swizzled

  const int tid  = threadIdx.x;
  const int lane = tid & 63;
  const int w    = tid >> 6;
  const int l15  = lane & 15;
  const int lg   = lane >> 4;

  int bid = blockIdx.x;
  bid = (bid & 7) * 32 + (bid >> 3);
  const int b     = bid >> 2;
  const int qrow0 = (bid & 3) * 256 + w * 32;

  const float scale2 = scale_p[0] * 1.4426950408889634f;
  const float* kb = kf + (size_t)b * LL * DD;

  #pragma unroll
  for (int it = 0; it < 16; ++it) {
    const int c = it * 512 + tid;
    const int row = c >> 3, slot = c & 7;
    const f32x4* s4 = (const f32x4*)(kb + (size_t)c * 8);
    f32x4 x0 = s4[0], x1 = s4[1];
    bf16x8 t;
    #pragma unroll
    for (int j = 0; j < 4; ++j) { t[j] = (__bf16)x0[j]; t[4 + j] = (__bf16)x1[j]; }
    *(bf16x8*)(Klds + row * 64 + ((slot * 8) ^ ((row & 7) * 8))) = t;
  }

  bf16x8 aq[2][2];
  #pragma unroll
  for (int u = 0; u < 2; ++u) {
    const float* qrow = q + ((size_t)b * LL + qrow0 + u * 16 + l15) * DD;
    #pragma unroll
    for (int s = 0; s < 2; ++s) {
      const f32x4* p4 = (const f32x4*)(qrow + s * 32 + lg * 8);
      f32x4 x0 = p4[0], x1 = p4[1];
      #pragma unroll
      for (int j = 0; j < 4; ++j) {
        aq[u][s][j]     = (__bf16)(x0[j] * scale2);
        aq[u][s][4 + j] = (__bf16)(x1[j] * scale2);
      }
    }
  }

  __syncthreads();

  const int xsw = (l15 & 7) * 8;
  float ls[2] = {0.f, 0.f};
  for (int kt = 0; kt < 32; ++kt) {
    bf16x8 bk[2][2];
    #pragma unroll
    for (int f = 0; f < 2; ++f)
      #pragma unroll
      for (int s = 0; s < 2; ++s)
        bk[f][s] = *(const bf16x8*)(Klds + (kt * 32 + f * 16 + l15) * 64
                                         + ((s * 32 + lg * 8) ^ xsw));
    #pragma unroll
    for (int u = 0; u < 2; ++u) {
      f32x4 sacc[2] = {{0.f,0.f,0.f,0.f},{0.f,0.f,0.f,0.f}};
      #pragma unroll
      for (int s = 0; s < 2; ++s)
        #pragma unroll
        for (int f = 0; f < 2; ++f)
          sacc[f] = __builtin_amdgcn_mfma_f32_16x16x32_bf16(bk[f][s], aq[u][s], sacc[f], 0, 0, 0);
      #pragma unroll
      for (int f = 0; f < 2; ++f)
        #pragma unroll
        for (int r = 0; r < 4; ++r)
          ls[u] += EXP2(sacc[f][r]);
    }
  }
  #pragma unroll
  for (int u = 0; u < 2; ++u) {
    ls[u] += __shfl_xor(ls[u], 16, 64);
    ls[u] += __shfl_xor(ls[u], 32, 64);
  }
  if (lg == 0) {
    float* rp = rlbuf + (size_t)b * LL + qrow0 + l15;
    rp[0]  = 1.0f / ls[0];
    rp[16] = 1.0f / ls[1];
  }
}

// ---------------- main: K+V halves in LDS, zero loads in store loop ---------
__global__ __launch_bounds__(512, 1)
void sdpa_store(const float* __restrict__ q, const float* __restrict__ kf,
                const __bf16* __restrict__ vt, const float* __restrict__ rlbuf,
                const float* __restrict__ scale_p, float* __restrict__ out) {
  extern __shared__ char smem[];
  __bf16* Klds = (__bf16*)smem;                        // [512][64] swizzled
  __bf16* Vlds = (__bf16*)(smem + HK * DD * 2);        // [64][512] swizzled
  float*  Pw   = (float*)(smem + 2 * HK * DD * 2);     // [8][16][PSTR]

  const int tid  = threadIdx.x;
  const int lane = tid & 63;
  const int w    = tid >> 6;
  const int l15  = lane & 15;
  const int lg   = lane >> 4;

  int bid = blockIdx.x;
  bid = (bid & 7) * 32 + (bid >> 3);
  const int b     = bid >> 2;
  const int qrow0 = (bid & 3) * 256 + w * 32;

  const float scale2 = scale_p[0] * 1.4426950408889634f;
  const float* kb  = kf + (size_t)b * LL * DD;
  const __bf16* vb = vt + (size_t)b * DD * LL;
  float* ctxb  = out + ((size_t)b * LL + qrow0) * DD;
  float* attnb = out + (size_t)NB * LL * DD + (size_t)b * LL * LL
               + (size_t)qrow0 * LL;

  // ---- Q fragments + normalizers ----
  bf16x8 aq[2][2];
  #pragma unroll
  for (int u = 0; u < 2; ++u) {
    const float* qrow = q + ((size_t)b * LL + qrow0 + u * 16 + l15) * DD;
    #pragma unroll
    for (int s = 0; s < 2; ++s) {
      const f32x4* p4 = (const f32x4*)(qrow + s * 32 + lg * 8);
      f32x4 x0 = p4[0], x1 = p4[1];
      #pragma unroll
      for (int j = 0; j < 4; ++j) {
        aq[u][s][j]     = (__bf16)(x0[j] * scale2);
        aq[u][s][4 + j] = (__bf16)(x1[j] * scale2);
      }
    }
  }
  const float* rlp = rlbuf + (size_t)b * LL + qrow0 + l15;
  const float rl[2] = {rlp[0], rlp[16]};

  const int xsw = (l15 & 7) * 8;
  float* prow  = Pw + (w * 16 + l15) * PSTR;          // write side (q = l15)
  const int srl = lane >> 3;                          // store row-in-8
  const int src8 = (lane & 7) * 4;                    // store col (fp32)
  const float* psr = Pw + (w * 16) * PSTR;            // store-read base

  f32x4 cacc[2][4];
  #pragma unroll
  for (int u = 0; u < 2; ++u)
    #pragma unroll
    for (int g = 0; g < 4; ++g)
      cacc[u][g] = (f32x4){0.f, 0.f, 0.f, 0.f};

  for (int h = 0; h < 2; ++h) {
    // ---- stage this half: K fp32->bf16 swizzled, V^T bf16 swizzled ----
    __syncthreads();   // previous half fully consumed
    #pragma unroll
    for (int it = 0; it < 8; ++it) {
      const int c = it * 512 + tid;                   // 4096 chunks of 8
      const int row = c >> 3, slot = c & 7;
      const f32x4* s4 = (const f32x4*)(kb + ((size_t)(h * HK + row) * DD) + slot * 8);
      f32x4 x0 = s4[0], x1 = s4[1];
      bf16x8 t;
      #pragma unroll
      for (int j = 0; j < 4; ++j) { t[j] = (__bf16)x0[j]; t[4 + j] = (__bf16)x1[j]; }
      *(bf16x8*)(Klds + row * 64 + ((slot * 8) ^ ((row & 7) * 8))) = t;

      const int d = c >> 6, ks = c & 63;
      bf16x8 tv = *(const bf16x8*)(vb + (size_t)d * LL + h * HK + ks * 8);
      *(bf16x8*)(Vlds + d * HK + ((ks * 8) ^ ((d & 7) * 8))) = tv;
    }
    __syncthreads();

    for (int kt = 0; kt < HK / 32; ++kt) {
      bf16x8 bk[2][2];
      #pragma unroll
      for (int f = 0; f < 2; ++f)
        #pragma unroll
        for (int s = 0; s < 2; ++s)
          bk[f][s] = *(const bf16x8*)(Klds + (kt * 32 + f * 16 + l15) * 64
                                           + ((s * 32 + lg * 8) ^ xsw));
      bf16x8 bv[4];
      #pragma unroll
      for (int g = 0; g < 4; ++g)
        bv[g] = *(const bf16x8*)(Vlds + (g * 16 + l15) * HK
                                      + ((kt * 32 + lg * 8) ^ xsw));

      #pragma unroll
      for (int u = 0; u < 2; ++u) {
        f32x4 sacc[2] = {{0.f,0.f,0.f,0.f},{0.f,0.f,0.f,0.f}};
        #pragma unroll
        for (int s = 0; s < 2; ++s)
          #pragma unroll
          for (int f = 0; f < 2; ++f)
            sacc[f] = __builtin_amdgcn_mfma_f32_16x16x32_bf16(bk[f][s], aq[u][s], sacc[f], 0, 0, 0);

        // p = exp2(s) * rl -> fp32 P tile in LDS (write: q=l15, k=f*16+lg*4+r)
        #pragma unroll
        for (int f = 0; f < 2; ++f) {
          f32x4 pv;
          #pragma unroll
          for (int r = 0; r < 4; ++r)
            pv[r] = EXP2(sacc[f][r]) * rl[u];
          *(f32x4*)(prow + f * 16 + lg * 4) = pv;
        }

        // PV A-operand: rows l15, k-chunk lg*8 (fp32 -> bf16)
        f32x4 p0 = *(const f32x4*)(prow + lg * 8);
        f32x4 p1 = *(const f32x4*)(prow + lg * 8 + 4);
        bf16x8 pa;
        #pragma unroll
        for (int j = 0; j < 4; ++j) { pa[j] = (__bf16)p0[j]; pa[4 + j] = (__bf16)p1[j]; }
        #pragma unroll
        for (int g = 0; g < 4; ++g)
          cacc[u][g] = __builtin_amdgcn_mfma_f32_16x16x32_bf16(pa, bv[g], cacc[u][g], 0, 0, 0);

        // line-perfect attn stores: 2 instrs, each 8 rows x 128 B full lines
        #pragma unroll
        for (int j = 0; j < 2; ++j) {
          const int srow = j * 8 + srl;
          f32x4 sp = *(const f32x4*)(psr + srow * PSTR + src8);
          *(f32x4*)(attnb + (size_t)(u * 16 + srow) * LL
                          + h * HK + kt * 32 + src8) = sp;
        }
      }
    }
  }

  // ---- context epilogue ----
  #pragma unroll
  for (int u = 0; u < 2; ++u)
    #pragma unroll
    for (int g = 0; g < 4; ++g)
      #pragma unroll
      for (int r = 0; r < 4; ++r)
        ctxb[(size_t)(u * 16 + lg * 4 + r) * DD + g * 16 + l15] = cacc[u][g][r];
}

// ====================== fallback (R1 kernel, proven) ========================
#define BQ 64
#define BK 32
#define KSTRIDE 72
#define VSTRIDE 40
#define PSTRIDE 48

__global__ __launch_bounds__(256, 4)
void sdpa_fallback(const float* __restrict__ q, const float* __restrict__ k,
                   const float* __restrict__ v, const float* __restrict__ scale_p,
                   float* __restrict__ out) {
  const int tid  = threadIdx.x;
  const int lane = tid & 63;
  const int w    = tid >> 6;
  int bid = blockIdx.x;
  bid = (bid & 7) * 128 + (bid >> 3);
  const int b    = bid >> 4;
  const int qblk = (bid & 15) * BQ;

  __shared__ __bf16 Ks[BK * KSTRIDE];
  __shared__ __bf16 Vs[DD * VSTRIDE];
  __shared__ __bf16 Pp[4][16 * PSTRIDE];

  const float scale = scale_p[0];
  const float* qb = q + ((size_t)b * LL + qblk) * DD;
  const float* kb = k + (size_t)b * LL * DD;
  const float* vb = v + (size_t)b * LL * DD;
  float* ctx  = out + ((size_t)b * LL + qblk) * DD;
  float* attn = out + (size_t)NB * LL * DD + (size_t)b * LL * LL + (size_t)qblk * LL;

  const int l15 = lane & 15;
  const int lg  = lane >> 4;
  const int dchunk = lg * 8;

  bf16x8 aq[2];
  {
    const float* qrow = qb + (size_t)(w * 16 + l15) * DD;
    #pragma unroll
    for (int s = 0; s < 2; ++s) {
      const f32x4* p4 = (const f32x4*)(qrow + s * 32 + dchunk);
      f32x4 x0 = p4[0], x1 = p4[1];
      #pragma unroll
      for (int j = 0; j < 4; ++j) {
        aq[s][j]     = (__bf16)(x0[j] * scale);
        aq[s][4 + j] = (__bf16)(x1[j] * scale);
      }
    }
  }

  const int srow = tid >> 3;
  const int sd0  = (tid & 7) * 8;

  float lpart[4] = {0.f, 0.f, 0.f, 0.f};
  for (int kt = 0; kt < LL / BK; ++kt) {
    __syncthreads();
    {
      const f32x4* src = (const f32x4*)(kb + (size_t)(kt * BK + srow) * DD + sd0);
      f32x4 x0 = src[0], x1 = src[1];
      bf16x8 t;
      #pragma unroll
      for (int j = 0; j < 4; ++j) { t[j] = (__bf16)x0[j]; t[4 + j] = (__bf16)x1[j]; }
      *(bf16x8*)&Ks[srow * KSTRIDE + sd0] = t;
    }
    __syncthreads();
    f32x4 sacc[2] = {{0.f,0.f,0.f,0.f},{0.f,0.f,0.f,0.f}};
    #pragma unroll
    for (int s = 0; s < 2; ++s)
      #pragma unroll
      for (int f = 0; f < 2; ++f) {
        bf16x8 bk = *(const bf16x8*)&Ks[(f * 16 + l15) * KSTRIDE + s * 32 + dchunk];
        sacc[f] = __builtin_amdgcn_mfma_f32_16x16x32_bf16(aq[s], bk, sacc[f], 0, 0, 0);
      }
    #pragma unroll
    for (int f = 0; f < 2; ++f)
      #pragma unroll
      for (int r = 0; r < 4; ++r)
        lpart[r] += __expf(sacc[f][r]);
  }
  #pragma unroll
  for (int m = 1; m < 16; m <<= 1)
    #pragma unroll
    for (int r = 0; r < 4; ++r)
      lpart[r] += __shfl_xor(lpart[r], m, 64);
  float rl[4];
  #pragma unroll
  for (int r = 0; r < 4; ++r) rl[r] = 1.0f / lpart[r];

  f32x4 cacc[4] = {{0.f,0.f,0.f,0.f},{0.f,0.f,0.f,0.f},
                   {0.f,0.f,0.f,0.f},{0.f,0.f,0.f,0.f}};
  for (int kt = 0; kt < LL / BK; ++kt) {
    __syncthreads();
    {
      const f32x4* src = (const f32x4*)(kb + (size_t)(kt * BK + srow) * DD + sd0);
      f32x4 x0 = src[0], x1 = src[1];
      bf16x8 t;
      #pragma unroll
      for (int j = 0; j < 4; ++j) { t[j] = (__bf16)x0[j]; t[4 + j] = (__bf16)x1[j]; }
      *(bf16x8*)&Ks[srow * KSTRIDE + sd0] = t;
      const f32x4* vsrc = (const f32x4*)(vb + (size_t)(kt * BK + srow) * DD + sd0);
      f32x4 y0 = vsrc[0], y1 = vsrc[1];
      #pragma unroll
      for (int j = 0; j < 4; ++j) {
        Vs[(sd0 + j)     * VSTRIDE + srow] = (__bf16)y0[j];
        Vs[(sd0 + 4 + j) * VSTRIDE + srow] = (__bf16)y1[j];
      }
    }
    __syncthreads();
    f32x4 sacc[2] = {{0.f,0.f,0.f,0.f},{0.f,0.f,0.f,0.f}};
    #pragma unroll
    for (int s = 0; s < 2; ++s)
      #pragma unroll
      for (int f = 0; f < 2; ++f) {
        bf16x8 bk = *(const bf16x8*)&Ks[(f * 16 + l15) * KSTRIDE + s * 32 + dchunk];
        sacc[f] = __builtin_amdgcn_mfma_f32_16x16x32_bf16(aq[s], bk, sacc[f], 0, 0, 0);
      }
    #pragma unroll
    for (int f = 0; f < 2; ++f)
      #pragma unroll
      for (int r = 0; r < 4; ++r) {
        const int row = lg * 4 + r;
        float p = __expf(sacc[f][r]) * rl[r];
        attn[(size_t)(w * 16 + row) * LL + (kt * BK + f * 16 + l15)] = p;
        Pp[w][row * PSTRIDE + f * 16 + l15] = (__bf16)p;
      }
    bf16x8 pa = *(const bf16x8*)&Pp[w][l15 * PSTRIDE + lg * 8];
    #pragma unroll
    for (int g = 0; g < 4; ++g) {
      bf16x8 bv = *(const bf16x8*)&Vs[(g * 16 + l15) * VSTRIDE + lg * 8];
      cacc[g] = __builtin_amdgcn_mfma_f32_16x16x32_bf16(pa, bv, cacc[g], 0, 0, 0);
    }
  }
  #pragma unroll
  for (int g = 0; g < 4; ++g)
    #pragma unroll
    for (int r = 0; r < 4; ++r)
      ctx[(size_t)(w * 16 + lg * 4 + r) * DD + g * 16 + l15] = cacc[g][r];
}

extern "C" void kernel_launch(void* const* d_in, const int* in_sizes, int n_in,
                              void* d_out, int out_size, void* d_ws, size_t ws_size,
                              hipStream_t stream) {
  const float* q = (const float*)d_in[0];
  const float* k = (const float*)d_in[1];
  const float* v = (const float*)d_in[2];
  const float* s = (const float*)d_in[3];
  float* out = (float*)d_out;

  if (ws_size >= WS_NEED) {
    __bf16* vt = (__bf16*)((char*)d_ws + WS_VT_OFF);
    float*  rl = (float*)((char*)d_ws + WS_RL_OFF);
    preconvert_v<<<dim3(NB * (LL / 64)), dim3(256), 0, stream>>>(v, vt);
    (void)hipFuncSetAttribute((const void*)lsum_kernel,
                              hipFuncAttributeMaxDynamicSharedMemorySize, LSUM_LDS);
    lsum_kernel<<<dim3(256), dim3(512), LSUM_LDS, stream>>>(q, k, s, rl);
    (void)hipFuncSetAttribute((const void*)sdpa_store,
                              hipFuncAttributeMaxDynamicSharedMemorySize, MAIN_LDS);
    sdpa_store<<<dim3(256), dim3(512), MAIN_LDS, stream>>>(q, k, vt, rl, s, out);
  } else {
    sdpa_fallback<<<dim3(NB * (LL / 64)), dim3(256), 0, stream>>>(q, k, v, s, out);
  }
}